// Round 12
// baseline (3672.199 us; speedup 1.0000x reference)
//
#include <hip/hip_runtime.h>
#include <hip/hip_bf16.h>

// LSTM_Net round 22: two-group (A/B) pipelined sub-steps per XCD domain.
// r21 exonerated flag-line sharing (neutral/worse; packed layout restored).
// Counters say 85% of the 6.4us period is latency-shaped waiting that five
// rounds of component theories failed to localize. r22 hides ALL of it:
// split each domain's 16 rows into two INDEPENDENT 8-row recurrences A,B
// advancing at alternating sub-steps. Every poll's target flag was published
// one half-step (~0.9us) earlier -> store->MALL->detect propagation hides
// under the other group's compute. M=8 in 16-row MFMA tiles (2x MFMA count,
// cheap at 5% util); weights shared across groups (AGPR/LDS unchanged).
// Sync primitives = r19/r20 proven (sc1 + AGENT_LD, packed flags, raw BAR,
// counted vmcnt). fx drain-guarantee via vmcnt-FIFO across sub-steps:
// at A[s]'s vmcnt(1), h1xB[s-1] is retired -> publish fxB=s there; at
// B[s]'s vmcnt(1), h1xA[s] retired -> publish fxA=s+1.
// ctrs (ints): [0..7] roles; fself[xcd]=1024+xcd*64 (A at +fidx, B at
// +32+fidx); fx[g]=2048+g*64+fidx (8 groups); done at 4096.

#define B_  64
#define T_  256
#define IN_ 64
#define H_  768
#define G_  3072   // 4*H
#define K0_ 832    // IN_ + H_
#define K1_ 1536   // 2*H_
#define NWGT 256
#define GS8 6144   // per (t,group8) ring slot elems = 96cbw * 8rows * 8cols

typedef __bf16 bf16_t;
typedef bf16_t bf16x8 __attribute__((ext_vector_type(8)));
typedef float  f32x4  __attribute__((ext_vector_type(4)));

__device__ __forceinline__ unsigned short f2bf(float f) {
    union { float f; unsigned u; } v; v.f = f;
    unsigned r = v.u + 0x7FFFu + ((v.u >> 16) & 1u);
    return (unsigned short)(r >> 16);
}
__device__ __forceinline__ float fast_sigm(float x) {
    float e = __builtin_amdgcn_exp2f(-1.44269504f * x);
    return __builtin_amdgcn_rcpf(1.0f + e);
}
__device__ __forceinline__ float fast_tanh(float x) {
    float e = __builtin_amdgcn_exp2f(2.88539008f * x);
    return (e - 1.0f) * __builtin_amdgcn_rcpf(e + 1.0f);
}
__device__ __forceinline__ void st_llc_u32(unsigned* p, unsigned v) {
    asm volatile("global_store_dword %0, %1, off sc1" :: "v"(p), "v"(v) : "memory");
}
#define MFMA16(a, b, c) __builtin_amdgcn_mfma_f32_16x16x32_bf16((a), (b), (c), 0, 0, 0)
#define AGENT_LD(p) __hip_atomic_load((p), __ATOMIC_RELAXED, __HIP_MEMORY_SCOPE_AGENT)
#define PIN8A(v) asm volatile("" : "+a"(v))
#define BAR() do { __builtin_amdgcn_s_barrier(); \
                   asm volatile("" ::: "memory"); } while (0)
#define WAITV0() asm volatile("s_waitcnt vmcnt(0)" ::: "memory")
#define WAITV1() asm volatile("s_waitcnt vmcnt(1)" ::: "memory")

// ---------------- prep ----------------
__global__ __launch_bounds__(256) void prep_kernel(
    const float* __restrict__ x,
    const float* __restrict__ Wih0, const float* __restrict__ Whh0,
    const float* __restrict__ bih0, const float* __restrict__ bhh0,
    const float* __restrict__ Wih1, const float* __restrict__ Whh1,
    const float* __restrict__ bih1, const float* __restrict__ bhh1,
    unsigned short* __restrict__ xsT,    // [T][B][64]
    unsigned short* __restrict__ W0cat,  // [3072][832]
    unsigned short* __restrict__ W1cat,  // [3072][1536]
    float* __restrict__ bias0, float* __restrict__ bias1,
    int* __restrict__ ctrs)              // [16384]
{
    int i = blockIdx.x * blockDim.x + threadIdx.x;
    int stride = gridDim.x * blockDim.x;
    for (int j = i; j < B_ * T_ * IN_; j += stride) {
        int b = j >> 14;
        int t = (j >> 6) & (T_ - 1);
        int k = j & (IN_ - 1);
        xsT[(((size_t)t * B_) + b) * IN_ + k] = f2bf(x[j] * (1.0f / 1.5f));
    }
    for (int j = i; j < G_ * IN_; j += stride) {
        int r = j >> 6; int k = j & 63;
        W0cat[(size_t)r * K0_ + k] = f2bf(Wih0[j]);
    }
    for (int j = i; j < G_ * H_; j += stride) {
        int r = j / H_; int k = j - r * H_;
        W0cat[(size_t)r * K0_ + IN_ + k] = f2bf(Whh0[j]);
        W1cat[(size_t)r * K1_ + k]       = f2bf(Wih1[j]);
        W1cat[(size_t)r * K1_ + H_ + k]  = f2bf(Whh1[j]);
    }
    for (int j = i; j < G_; j += stride) {
        bias0[j] = bih0[j] + bhh0[j];
        bias1[j] = bih1[j] + bhh1[j];
    }
    for (int j = i; j < 16384; j += stride) ctrs[j] = 0;
}

// ---------------- persistent XCD-domain recurrence, A/B pipelined ----------
__global__ __launch_bounds__(256, 1) void lstm_persistent(
    const unsigned short* __restrict__ xsT,
    const unsigned short* __restrict__ W0cat,
    const unsigned short* __restrict__ W1cat,
    const float* __restrict__ bias0, const float* __restrict__ bias1,
    unsigned short* __restrict__ h1loc,  // [T][8][GS8] plain/local
    unsigned short* __restrict__ h1x,    // [T][8][GS8] sc1/cross
    unsigned short* __restrict__ h2loc,  // [T][8][GS8] plain/local
    float* __restrict__ hf32,            // [B][H] fp32 (t = T-1)
    int* __restrict__ ctrs)
{
    __shared__ unsigned short ldsb[4][8][8];
    // 144KB weight stage (L1 waves: 36 frags x 1KB each). Forces 1 WG/CU.
    __shared__ char wstage[4][36][1024];
    __shared__ int role_s;

    const int tid  = threadIdx.x;
    const int lane = tid & 63;
    const int wave = tid >> 6;

    int xcd;
    asm volatile("s_getreg_b32 %0, hwreg(HW_REG_XCC_ID)" : "=s"(xcd));
    xcd &= 7;

    if (tid == 0) role_s = atomicAdd(&ctrs[xcd], 1);
    __syncthreads();
    const int role = role_s;

    int* done = &ctrs[4096];

    // ---------- heater roles ----------
    if (role >= 24) {
        float a = 1.0f + (float)tid * 1e-7f;
        const float bm = 1.0000001f, cm = 1e-9f;
        for (;;) {
            for (int i = 0; i < 2048; i++)
                a = __builtin_fmaf(a, bm, cm);
            asm volatile("" : "+v"(a));
            int d = 0;
            if (lane == 0) d = AGENT_LD(done);
            d = __builtin_amdgcn_readfirstlane(d);
            if (d != 0) break;
        }
        return;
    }

    const int l  = xcd & 1;          // layer
    const int gA = (xcd >> 1) * 2;   // batch group A (8 rows)
    const int gB = gA + 1;           // batch group B
    const int cbw = role * 4 + wave; // H-col block 0..95 (8 cols each)
    const int c0  = cbw * 8;
    const int frow = lane & 15;
    const int q    = lane >> 4;
    const int kof  = q * 8;

    int fidx = lane; if (fidx >= 48) fidx -= 48; if (fidx >= 24) fidx -= 24;
    int* fs  = &ctrs[1024 + xcd * 64];   // self flags: A at +i, B at +32+i
    int* fxA = &ctrs[2048 + gA * 64];    // cross h1 flags group A
    int* fxB = &ctrs[2048 + gB * 64];    // cross h1 flags group B

    const unsigned short* Wc = l ? W1cat : W0cat;
    const int Kc = l ? K1_ : K0_;
    int q0 = frow >> 3, col0 = c0 + (frow & 7);
    const unsigned short* Bp0 = Wc + (size_t)(q0 * H_ + col0) * Kc + kof;       // gates i,f
    const unsigned short* Bp1 = Wc + (size_t)((2 + q0) * H_ + col0) * Kc + kof; // gates g,o

    const float* bias = l ? bias1 : bias0;
    const bool lowhalf = (lane & 15) < 8;
    const bool outl = lowhalf && (q < 2);   // M=8: rows 0..7 only
    const int ecol = c0 + (lane & 7);
    float bi = 0.f, bff = 0.f, bg = 0.f, bo = 0.f;
    if (lowhalf) {
        bi  = bias[0 * H_ + ecol];
        bff = bias[1 * H_ + ecol];
        bg  = bias[2 * H_ + ecol];
        bo  = bias[3 * H_ + ecol];
    }
    float cregA[4] = {0.f, 0.f, 0.f, 0.f};
    float cregB[4] = {0.f, 0.f, 0.f, 0.f};

    // consumer: chunk kj -> colblock (4kj+q), row frow&7, 8 cols
    const size_t aoff8 = (size_t)q * 64 + (size_t)(frow & 7) * 8;
    // producer: wave owns cbw; dword lane<32 -> (row=lane>>2, col=(lane&3)*2)
    const size_t stoff8 = (size_t)cbw * 64 + (size_t)(lane >> 2) * 8
                        + (size_t)(lane & 3) * 2;

    if (l == 0) {
        // ================= layer 0 domain =================
        bf16x8 Bw0[26], Bw1[26];
        #pragma unroll
        for (int k = 0; k < 26; k++) {
            Bw0[k] = *(const bf16x8*)(Bp0 + k * 32);
            Bw1[k] = *(const bf16x8*)(Bp1 + k * 32);
        }
        #pragma unroll
        for (int k = 0; k < 26; k++) { PIN8A(Bw0[k]); PIN8A(Bw1[k]); }
        for (int s = 0; s < T_; ++s) {
            // ---------------- sub-step A: compute h1_A[s] ----------------
            {
                f32x4 acc0 = {0.f, 0.f, 0.f, 0.f};
                f32x4 acc1 = {0.f, 0.f, 0.f, 0.f};
                const unsigned short* xsp =
                    xsT + ((size_t)s * B_ + gA * 8 + (frow & 7)) * IN_ + kof;
                bf16x8 ax0 = *(const bf16x8*)(xsp);
                bf16x8 ax1 = *(const bf16x8*)(xsp + 32);
                acc0 = MFMA16(ax0, Bw0[0], acc0);
                acc1 = MFMA16(ax0, Bw1[0], acc1);
                acc0 = MFMA16(ax1, Bw0[1], acc0);
                acc1 = MFMA16(ax1, Bw1[1], acc1);
                if (s > 0) {
                    if (wave == 0) {   // h1_A[s-1]: fsA >= s
                        const int* fp = &fs[fidx];
                        for (;;) {
                            int v = AGENT_LD(fp);
                            if (__all(v >= s)) break;
                            __builtin_amdgcn_s_sleep(1);
                        }
                    }
                    BAR();
                    const unsigned short* hr =
                        h1loc + ((size_t)(s - 1) * 8 + gA) * GS8 + aoff8;
                    bf16x8 a[24];
                    #pragma unroll
                    for (int kj = 0; kj < 24; kj++)
                        a[kj] = *(const bf16x8*)(hr + kj * 256);
                    #pragma unroll
                    for (int kj = 0; kj < 24; kj++) {
                        acc0 = MFMA16(a[kj], Bw0[kj + 2], acc0);
                        acc1 = MFMA16(a[kj], Bw1[kj + 2], acc1);
                    }
                } else {
                    BAR();
                }
                f32x4 pacc0, pacc1;
                #pragma unroll
                for (int j = 0; j < 4; j++) {
                    pacc0[j] = __shfl_xor(acc0[j], 8);
                    pacc1[j] = __shfl_xor(acc1[j], 8);
                }
                if (outl) {
                    #pragma unroll
                    for (int j = 0; j < 4; j++) {
                        float pi = acc0[j]  + bi;
                        float pf = pacc0[j] + bff;
                        float pg = acc1[j]  + bg;
                        float po = pacc1[j] + bo;
                        float cn = fast_sigm(pf) * cregA[j] + fast_sigm(pi) * fast_tanh(pg);
                        float hn = fast_sigm(po) * fast_tanh(cn);
                        cregA[j] = cn;
                        ldsb[wave][q * 4 + j][lane & 7] = f2bf(hn);
                    }
                }
                if (lane < 32) {
                    unsigned v = ((const unsigned*)&ldsb[wave][0][0])[lane];
                    size_t so = ((size_t)s * 8 + gA) * GS8 + stoff8;
                    *(unsigned*)(h1loc + so) = v;
                    st_llc_u32((unsigned*)(h1x + so), v);
                }
                WAITV1();   // retire h1locA (and older: h1xB[s-1] inclusive)
                BAR();
                if (tid == 0) {
                    st_llc_u32((unsigned*)&fs[fidx == 0 ? role : role], (unsigned)0);
                }
                if (tid == 0) {
                    st_llc_u32((unsigned*)&fs[role], (unsigned)(s + 1));      // fselfA
                    if (s > 0)
                        st_llc_u32((unsigned*)&fxB[role], (unsigned)s);       // h1xB[s-1] drained
                }
            }
            // ---------------- sub-step B: compute h1_B[s] ----------------
            {
                f32x4 acc0 = {0.f, 0.f, 0.f, 0.f};
                f32x4 acc1 = {0.f, 0.f, 0.f, 0.f};
                const unsigned short* xsp =
                    xsT + ((size_t)s * B_ + gB * 8 + (frow & 7)) * IN_ + kof;
                bf16x8 ax0 = *(const bf16x8*)(xsp);
                bf16x8 ax1 = *(const bf16x8*)(xsp + 32);
                acc0 = MFMA16(ax0, Bw0[0], acc0);
                acc1 = MFMA16(ax0, Bw1[0], acc1);
                acc0 = MFMA16(ax1, Bw0[1], acc0);
                acc1 = MFMA16(ax1, Bw1[1], acc1);
                if (s > 0) {
                    if (wave == 0) {   // h1_B[s-1]: fsB >= s
                        const int* fp = &fs[32 + fidx];
                        for (;;) {
                            int v = AGENT_LD(fp);
                            if (__all(v >= s)) break;
                            __builtin_amdgcn_s_sleep(1);
                        }
                    }
                    BAR();
                    const unsigned short* hr =
                        h1loc + ((size_t)(s - 1) * 8 + gB) * GS8 + aoff8;
                    bf16x8 a[24];
                    #pragma unroll
                    for (int kj = 0; kj < 24; kj++)
                        a[kj] = *(const bf16x8*)(hr + kj * 256);
                    #pragma unroll
                    for (int kj = 0; kj < 24; kj++) {
                        acc0 = MFMA16(a[kj], Bw0[kj + 2], acc0);
                        acc1 = MFMA16(a[kj], Bw1[kj + 2], acc1);
                    }
                } else {
                    BAR();
                }
                f32x4 pacc0, pacc1;
                #pragma unroll
                for (int j = 0; j < 4; j++) {
                    pacc0[j] = __shfl_xor(acc0[j], 8);
                    pacc1[j] = __shfl_xor(acc1[j], 8);
                }
                if (outl) {
                    #pragma unroll
                    for (int j = 0; j < 4; j++) {
                        float pi = acc0[j]  + bi;
                        float pf = pacc0[j] + bff;
                        float pg = acc1[j]  + bg;
                        float po = pacc1[j] + bo;
                        float cn = fast_sigm(pf) * cregB[j] + fast_sigm(pi) * fast_tanh(pg);
                        float hn = fast_sigm(po) * fast_tanh(cn);
                        cregB[j] = cn;
                        ldsb[wave][q * 4 + j][lane & 7] = f2bf(hn);
                    }
                }
                if (lane < 32) {
                    unsigned v = ((const unsigned*)&ldsb[wave][0][0])[lane];
                    size_t so = ((size_t)s * 8 + gB) * GS8 + stoff8;
                    *(unsigned*)(h1loc + so) = v;
                    st_llc_u32((unsigned*)(h1x + so), v);
                }
                WAITV1();   // retire h1locB (and older: h1xA[s] inclusive)
                BAR();
                if (tid == 0) {
                    st_llc_u32((unsigned*)&fs[32 + role], (unsigned)(s + 1)); // fselfB
                    st_llc_u32((unsigned*)&fxA[role], (unsigned)(s + 1));     // h1xA[s] drained
                }
            }
        }
        WAITV0();
        BAR();
        if (tid == 0) st_llc_u32((unsigned*)&fxB[role], (unsigned)T_);
    } else {
        // ================= layer 1 domain =================
        bf16x8 Bw0[24], Bw1[24];   // h1-half weights
        #pragma unroll
        for (int k = 0; k < 24; k++) {
            Bw0[k] = *(const bf16x8*)(Bp0 + k * 32);
            Bw1[k] = *(const bf16x8*)(Bp1 + k * 32);
        }
        bf16x8 Cw0[6], Cw1[6];     // h2-half ki 0..5
        #pragma unroll
        for (int k = 0; k < 6; k++) {
            Cw0[k] = *(const bf16x8*)(Bp0 + (24 + k) * 32);
            Cw1[k] = *(const bf16x8*)(Bp1 + (24 + k) * 32);
        }
        #pragma unroll
        for (int k = 0; k < 24; k++) { PIN8A(Bw0[k]); PIN8A(Bw1[k]); }
        #pragma unroll
        for (int k = 0; k < 6; k++)  { PIN8A(Cw0[k]); PIN8A(Cw1[k]); }
        #pragma unroll
        for (int f = 0; f < 18; f++) {   // stage h2-half ki = 6+f
            bf16x8 b0 = *(const bf16x8*)(Bp0 + (30 + f) * 32);
            bf16x8 b1 = *(const bf16x8*)(Bp1 + (30 + f) * 32);
            *(bf16x8*)&wstage[wave][2 * f][lane * 16]     = b0;
            *(bf16x8*)&wstage[wave][2 * f + 1][lane * 16] = b1;
        }
        for (int s = 1; s <= T_; ++s) {
            const int t = s - 1;
            // ---------------- sub-step A: compute h2_A[t] ----------------
            {
                if (wave == 0) {   // h1_A[t] ready cross-die: fxA >= s
                    const int* fp = &fxA[fidx];
                    for (;;) {
                        int v = AGENT_LD(fp);
                        if (__all(v >= s)) break;
                        __builtin_amdgcn_s_sleep(1);
                    }
                }
                if (wave == 1 && t > 0) {   // h2_A[t-1] local: fsA >= t
                    const int* fp = &fs[fidx];
                    for (;;) {
                        int v = AGENT_LD(fp);
                        if (__all(v >= t)) break;
                        __builtin_amdgcn_s_sleep(1);
                    }
                }
                BAR();
                f32x4 acc0 = {0.f, 0.f, 0.f, 0.f};
                f32x4 acc1 = {0.f, 0.f, 0.f, 0.f};
                const unsigned short* h1r =
                    h1x + ((size_t)t * 8 + gA) * GS8 + aoff8;
                if (t > 0) {
                    const unsigned short* h2r =
                        h2loc + ((size_t)(t - 1) * 8 + gA) * GS8 + aoff8;
                    bf16x8 a2[24];
                    #pragma unroll
                    for (int ki = 0; ki < 24; ki++)
                        a2[ki] = *(const bf16x8*)(h2r + ki * 256);
                    bf16x8 a1[24];
                    #pragma unroll
                    for (int ki = 0; ki < 24; ki++)
                        a1[ki] = *(const bf16x8*)(h1r + ki * 256);
                    #pragma unroll
                    for (int ki = 0; ki < 6; ki++) {
                        acc0 = MFMA16(a2[ki], Cw0[ki], acc0);
                        acc1 = MFMA16(a2[ki], Cw1[ki], acc1);
                    }
                    #pragma unroll
                    for (int ki = 6; ki < 24; ki++) {
                        int f = ki - 6;
                        bf16x8 b0 = *(const bf16x8*)&wstage[wave][2 * f][lane * 16];
                        bf16x8 b1 = *(const bf16x8*)&wstage[wave][2 * f + 1][lane * 16];
                        acc0 = MFMA16(a2[ki], b0, acc0);
                        acc1 = MFMA16(a2[ki], b1, acc1);
                    }
                    #pragma unroll
                    for (int ki = 0; ki < 24; ki++) {
                        acc0 = MFMA16(a1[ki], Bw0[ki], acc0);
                        acc1 = MFMA16(a1[ki], Bw1[ki], acc1);
                    }
                } else {
                    bf16x8 a1[24];
                    #pragma unroll
                    for (int ki = 0; ki < 24; ki++)
                        a1[ki] = *(const bf16x8*)(h1r + ki * 256);
                    #pragma unroll
                    for (int ki = 0; ki < 24; ki++) {
                        acc0 = MFMA16(a1[ki], Bw0[ki], acc0);
                        acc1 = MFMA16(a1[ki], Bw1[ki], acc1);
                    }
                }
                f32x4 pacc0, pacc1;
                #pragma unroll
                for (int j = 0; j < 4; j++) {
                    pacc0[j] = __shfl_xor(acc0[j], 8);
                    pacc1[j] = __shfl_xor(acc1[j], 8);
                }
                if (outl) {
                    #pragma unroll
                    for (int j = 0; j < 4; j++) {
                        float pi = acc0[j]  + bi;
                        float pf = pacc0[j] + bff;
                        float pg = acc1[j]  + bg;
                        float po = pacc1[j] + bo;
                        float cn = fast_sigm(pf) * cregA[j] + fast_sigm(pi) * fast_tanh(pg);
                        float hn = fast_sigm(po) * fast_tanh(cn);
                        cregA[j] = cn;
                        ldsb[wave][q * 4 + j][lane & 7] = f2bf(hn);
                        if (t == T_ - 1)
                            hf32[(size_t)(gA * 8 + q * 4 + j) * H_ + ecol] = hn;
                    }
                }
                if (lane < 32) {
                    unsigned v = ((const unsigned*)&ldsb[wave][0][0])[lane];
                    *(unsigned*)(h2loc + ((size_t)t * 8 + gA) * GS8 + stoff8) = v;
                }
                WAITV0();
                BAR();
                if (tid == 0)
                    st_llc_u32((unsigned*)&fs[role], (unsigned)s);   // fselfA
            }
            // ---------------- sub-step B: compute h2_B[t] ----------------
            {
                if (wave == 0) {   // h1_B[t] ready cross-die: fxB >= s
                    const int* fp = &fxB[fidx];
                    for (;;) {
                        int v = AGENT_LD(fp);
                        if (__all(v >= s)) break;
                        __builtin_amdgcn_s_sleep(1);
                    }
                }
                if (wave == 1 && t > 0) {   // h2_B[t-1] local: fsB >= t
                    const int* fp = &fs[32 + fidx];
                    for (;;) {
                        int v = AGENT_LD(fp);
                        if (__all(v >= t)) break;
                        __builtin_amdgcn_s_sleep(1);
                    }
                }
                BAR();
                f32x4 acc0 = {0.f, 0.f, 0.f, 0.f};
                f32x4 acc1 = {0.f, 0.f, 0.f, 0.f};
                const unsigned short* h1r =
                    h1x + ((size_t)t * 8 + gB) * GS8 + aoff8;
                if (t > 0) {
                    const unsigned short* h2r =
                        h2loc + ((size_t)(t - 1) * 8 + gB) * GS8 + aoff8;
                    bf16x8 a2[24];
                    #pragma unroll
                    for (int ki = 0; ki < 24; ki++)
                        a2[ki] = *(const bf16x8*)(h2r + ki * 256);
                    bf16x8 a1[24];
                    #pragma unroll
                    for (int ki = 0; ki < 24; ki++)
                        a1[ki] = *(const bf16x8*)(h1r + ki * 256);
                    #pragma unroll
                    for (int ki = 0; ki < 6; ki++) {
                        acc0 = MFMA16(a2[ki], Cw0[ki], acc0);
                        acc1 = MFMA16(a2[ki], Cw1[ki], acc1);
                    }
                    #pragma unroll
                    for (int ki = 6; ki < 24; ki++) {
                        int f = ki - 6;
                        bf16x8 b0 = *(const bf16x8*)&wstage[wave][2 * f][lane * 16];
                        bf16x8 b1 = *(const bf16x8*)&wstage[wave][2 * f + 1][lane * 16];
                        acc0 = MFMA16(a2[ki], b0, acc0);
                        acc1 = MFMA16(a2[ki], b1, acc1);
                    }
                    #pragma unroll
                    for (int ki = 0; ki < 24; ki++) {
                        acc0 = MFMA16(a1[ki], Bw0[ki], acc0);
                        acc1 = MFMA16(a1[ki], Bw1[ki], acc1);
                    }
                } else {
                    bf16x8 a1[24];
                    #pragma unroll
                    for (int ki = 0; ki < 24; ki++)
                        a1[ki] = *(const bf16x8*)(h1r + ki * 256);
                    #pragma unroll
                    for (int ki = 0; ki < 24; ki++) {
                        acc0 = MFMA16(a1[ki], Bw0[ki], acc0);
                        acc1 = MFMA16(a1[ki], Bw1[ki], acc1);
                    }
                }
                f32x4 pacc0, pacc1;
                #pragma unroll
                for (int j = 0; j < 4; j++) {
                    pacc0[j] = __shfl_xor(acc0[j], 8);
                    pacc1[j] = __shfl_xor(acc1[j], 8);
                }
                if (outl) {
                    #pragma unroll
                    for (int j = 0; j < 4; j++) {
                        float pi = acc0[j]  + bi;
                        float pf = pacc0[j] + bff;
                        float pg = acc1[j]  + bg;
                        float po = pacc1[j] + bo;
                        float cn = fast_sigm(pf) * cregB[j] + fast_sigm(pi) * fast_tanh(pg);
                        float hn = fast_sigm(po) * fast_tanh(cn);
                        cregB[j] = cn;
                        ldsb[wave][q * 4 + j][lane & 7] = f2bf(hn);
                        if (t == T_ - 1)
                            hf32[(size_t)(gB * 8 + q * 4 + j) * H_ + ecol] = hn;
                    }
                }
                if (lane < 32) {
                    unsigned v = ((const unsigned*)&ldsb[wave][0][0])[lane];
                    *(unsigned*)(h2loc + ((size_t)t * 8 + gB) * GS8 + stoff8) = v;
                }
                WAITV0();
                BAR();
                if (tid == 0)
                    st_llc_u32((unsigned*)&fs[32 + role], (unsigned)s);  // fselfB
            }
        }
        if (xcd == 7 && role == 0 && tid == 0) st_llc_u32((unsigned*)done, 1u);
    }
}

// ---------------- head ----------------
__global__ __launch_bounds__(256) void head_kernel(
    const float* __restrict__ hlast,
    const float* __restrict__ W1, const float* __restrict__ b1,
    const float* __restrict__ W2, const float* __restrict__ b2,
    float* __restrict__ out)
{
    __shared__ float hs[H_];
    __shared__ float partial[4];
    int b = blockIdx.x;
    int tid = threadIdx.x;
    for (int j = tid; j < H_; j += 256) hs[j] = hlast[(size_t)b * H_ + j];
    __syncthreads();
    float z = 0.f;
    const float* w = W1 + (size_t)tid * H_;
    for (int j = 0; j < H_; j++) z += hs[j] * w[j];
    z += b1[tid];
    z = z / (1.0f + fabsf(z));
    float p = z * W2[tid];
    #pragma unroll
    for (int off = 32; off > 0; off >>= 1) p += __shfl_down(p, off, 64);
    if ((tid & 63) == 0) partial[tid >> 6] = p;
    __syncthreads();
    if (tid == 0) {
        float s = partial[0] + partial[1] + partial[2] + partial[3];
        out[b] = (s + b2[0]) * 70.0f;
    }
}

extern "C" void kernel_launch(void* const* d_in, const int* in_sizes, int n_in,
                              void* d_out, int out_size, void* d_ws, size_t ws_size,
                              hipStream_t stream) {
    const float* x    = (const float*)d_in[0];
    const float* Wih0 = (const float*)d_in[1];
    const float* Whh0 = (const float*)d_in[2];
    const float* bih0 = (const float*)d_in[3];
    const float* bhh0 = (const float*)d_in[4];
    const float* Wih1 = (const float*)d_in[5];
    const float* Whh1 = (const float*)d_in[6];
    const float* bih1 = (const float*)d_in[7];
    const float* bhh1 = (const float*)d_in[8];
    const float* W1   = (const float*)d_in[9];
    const float* b1   = (const float*)d_in[10];
    const float* W2   = (const float*)d_in[11];
    const float* b2   = (const float*)d_in[12];
    float* out = (float*)d_out;

    const size_t RING = (size_t)T_ * 8 * GS8 * 2;   // 24 MB each

    char* w = (char*)d_ws;
    int* ctrs = (int*)w;                          w += 65536;
    unsigned short* h1loc = (unsigned short*)w;   w += RING;
    unsigned short* h1x   = (unsigned short*)w;   w += RING;
    unsigned short* h2loc = (unsigned short*)w;   w += RING;
    unsigned short* xsT   = (unsigned short*)w;   w += (size_t)B_ * T_ * IN_ * 2;
    unsigned short* W0cat = (unsigned short*)w;   w += (size_t)G_ * K0_ * 2;
    unsigned short* W1cat = (unsigned short*)w;   w += (size_t)G_ * K1_ * 2;
    float* bias0 = (float*)w;                     w += G_ * 4;
    float* bias1 = (float*)w;                     w += G_ * 4;
    float* hf32  = (float*)w;                     w += (size_t)B_ * H_ * 4;

    prep_kernel<<<1024, 256, 0, stream>>>(x, Wih0, Whh0, bih0, bhh0,
                                          Wih1, Whh1, bih1, bhh1,
                                          xsT, W0cat, W1cat, bias0, bias1, ctrs);
    lstm_persistent<<<NWGT, 256, 0, stream>>>(xsT, W0cat, W1cat, bias0, bias1,
                                              h1loc, h1x, h2loc, hf32, ctrs);
    head_kernel<<<B_, 256, 0, stream>>>(hf32, W1, b1, W2, b2, out);
}

// Round 13
// 2923.975 us; speedup vs baseline: 1.2559x; 1.2559x over previous
//
#include <hip/hip_runtime.h>
#include <hip/hip_bf16.h>

// LSTM_Net round 23: r20 base (r21/r22 reverted) + barrier-free waves with
// per-wave flags.
// r22 lesson: cost is per-SYNC-ROUND (max-over-producers visibility+detect),
// not payload; more rounds = worse. r20's residual coupling beyond the true
// all-to-all dep: B1 (4-wave lockstep behind wave0 poll) and B2 (publish
// waits for slowest sibling's drain). Waves share NO data intra-WG -> both
// barriers removed:
//   - per-wave flags (96/domain, idx = cbw = role*4+wave); each wave
//     publishes its own flag after ITS OWN vmcnt drain (lane 0 store).
//   - every wave polls for itself: 2 loads over 96 packed flags + __all;
//     L1 combines fx + fself conditions in one poll loop. Zero barriers in
//     the main loops (only the role-broadcast syncthreads at start).
//   - deferred fx publish per wave: after poll + WAITV0 (h1x[s-1] ack lands
//     during the poll window), lane0 publishes fx[cbw]=s.
// r11's collapse causes addressed: no replication (domain-local flags),
// AGPR-pinned weights + SSA load batches pin codegen, poll ends with a
// compiler memory fence.
// ctrs (ints): [0..7] roles; fself[xcd]=1024+xcd*128 (+96); fx[g]=3072+
// g*128 (+96); done at 4095.

#define B_  64
#define T_  256
#define IN_ 64
#define H_  768
#define G_  3072   // 4*H
#define K0_ 832    // IN_ + H_
#define K1_ 1536   // 2*H_
#define NWGT 256
#define GSLOT_ 12288   // per (t,group) ring slot elems = 96cbw * 16rows * 8cols

typedef __bf16 bf16_t;
typedef bf16_t bf16x8 __attribute__((ext_vector_type(8)));
typedef float  f32x4  __attribute__((ext_vector_type(4)));

__device__ __forceinline__ unsigned short f2bf(float f) {
    union { float f; unsigned u; } v; v.f = f;
    unsigned r = v.u + 0x7FFFu + ((v.u >> 16) & 1u);
    return (unsigned short)(r >> 16);
}
__device__ __forceinline__ float fast_sigm(float x) {
    float e = __builtin_amdgcn_exp2f(-1.44269504f * x);
    return __builtin_amdgcn_rcpf(1.0f + e);
}
__device__ __forceinline__ float fast_tanh(float x) {
    float e = __builtin_amdgcn_exp2f(2.88539008f * x);
    return (e - 1.0f) * __builtin_amdgcn_rcpf(e + 1.0f);
}
__device__ __forceinline__ void st_llc_u32(unsigned* p, unsigned v) {
    asm volatile("global_store_dword %0, %1, off sc1" :: "v"(p), "v"(v) : "memory");
}
#define MFMA16(a, b, c) __builtin_amdgcn_mfma_f32_16x16x32_bf16((a), (b), (c), 0, 0, 0)
#define AGENT_LD(p) __hip_atomic_load((p), __ATOMIC_RELAXED, __HIP_MEMORY_SCOPE_AGENT)
#define PIN8A(v) asm volatile("" : "+a"(v))
#define WAITV0() asm volatile("s_waitcnt vmcnt(0)" ::: "memory")
#define WAITV1() asm volatile("s_waitcnt vmcnt(1)" ::: "memory")

// Wave-parallel scan of 96 packed per-wave flags (2 loads + __all).
#define POLL96(base, e) do {                                           \
    const int* _f1 = &(base)[i1];                                      \
    const int* _f2 = &(base)[i2];                                      \
    for (;;) {                                                         \
        int _a = AGENT_LD(_f1);                                        \
        int _b = AGENT_LD(_f2);                                        \
        if (__all(_a >= (e) && _b >= (e))) break;                      \
        __builtin_amdgcn_s_sleep(1);                                   \
    }                                                                  \
    asm volatile("" ::: "memory");                                     \
} while (0)

// ---------------- prep ----------------
__global__ __launch_bounds__(256) void prep_kernel(
    const float* __restrict__ x,
    const float* __restrict__ Wih0, const float* __restrict__ Whh0,
    const float* __restrict__ bih0, const float* __restrict__ bhh0,
    const float* __restrict__ Wih1, const float* __restrict__ Whh1,
    const float* __restrict__ bih1, const float* __restrict__ bhh1,
    unsigned short* __restrict__ xsT,    // [T][B][64]
    unsigned short* __restrict__ W0cat,  // [3072][832]
    unsigned short* __restrict__ W1cat,  // [3072][1536]
    float* __restrict__ bias0, float* __restrict__ bias1,
    int* __restrict__ ctrs)              // [16384]
{
    int i = blockIdx.x * blockDim.x + threadIdx.x;
    int stride = gridDim.x * blockDim.x;
    for (int j = i; j < B_ * T_ * IN_; j += stride) {
        int b = j >> 14;
        int t = (j >> 6) & (T_ - 1);
        int k = j & (IN_ - 1);
        xsT[(((size_t)t * B_) + b) * IN_ + k] = f2bf(x[j] * (1.0f / 1.5f));
    }
    for (int j = i; j < G_ * IN_; j += stride) {
        int r = j >> 6; int k = j & 63;
        W0cat[(size_t)r * K0_ + k] = f2bf(Wih0[j]);
    }
    for (int j = i; j < G_ * H_; j += stride) {
        int r = j / H_; int k = j - r * H_;
        W0cat[(size_t)r * K0_ + IN_ + k] = f2bf(Whh0[j]);
        W1cat[(size_t)r * K1_ + k]       = f2bf(Wih1[j]);
        W1cat[(size_t)r * K1_ + H_ + k]  = f2bf(Whh1[j]);
    }
    for (int j = i; j < G_; j += stride) {
        bias0[j] = bih0[j] + bhh0[j];
        bias1[j] = bih1[j] + bhh1[j];
    }
    for (int j = i; j < 16384; j += stride) ctrs[j] = 0;
}

// ---------------- persistent XCD-domain recurrence, barrier-free ----------
__global__ __launch_bounds__(256, 1) void lstm_persistent(
    const unsigned short* __restrict__ xsT,
    const unsigned short* __restrict__ W0cat,
    const unsigned short* __restrict__ W1cat,
    const float* __restrict__ bias0, const float* __restrict__ bias1,
    unsigned short* __restrict__ h1loc,  // [T][4g][96cbw][16][8] plain/local
    unsigned short* __restrict__ h1x,    // [T][4g][96cbw][16][8] sc1/cross
    unsigned short* __restrict__ h2loc,  // [T][4g][96cbw][16][8] plain/local
    float* __restrict__ hf32,            // [B][H] fp32 (t = T-1)
    int* __restrict__ ctrs)
{
    __shared__ unsigned short ldsb[4][16][8];
    // 144KB weight stage (L1 waves: 36 frags x 1KB each). Forces 1 WG/CU.
    __shared__ char wstage[4][36][1024];
    __shared__ int role_s;

    const int tid  = threadIdx.x;
    const int lane = tid & 63;
    const int wave = tid >> 6;

    int xcd;
    asm volatile("s_getreg_b32 %0, hwreg(HW_REG_XCC_ID)" : "=s"(xcd));
    xcd &= 7;

    if (tid == 0) role_s = atomicAdd(&ctrs[xcd], 1);
    __syncthreads();   // role broadcast only; no barriers in main loops
    const int role = role_s;

    int* done = &ctrs[4095];

    // ---------- heater roles: pin GFX clock; poll dedicated done line ------
    if (role >= 24) {
        float a = 1.0f + (float)tid * 1e-7f;
        const float bm = 1.0000001f, cm = 1e-9f;
        for (;;) {
            for (int i = 0; i < 2048; i++)
                a = __builtin_fmaf(a, bm, cm);
            asm volatile("" : "+v"(a));
            int d = 0;
            if (lane == 0) d = AGENT_LD(done);
            d = __builtin_amdgcn_readfirstlane(d);
            if (d != 0) break;
        }
        return;
    }

    const int l  = xcd & 1;          // layer handled by this XCD
    const int g  = xcd >> 1;         // batch group (16 rows)
    const int m0 = g * 16;           // group's batch-row base
    const int cbw = role * 4 + wave; // H-col block 0..95 (8 cols each) = flag idx
    const int c0  = cbw * 8;
    const int frow = lane & 15;
    const int q    = lane >> 4;
    const int kof  = q * 8;

    const int i1 = lane;             // flag scan: 0..63
    const int i2 = 64 + (lane & 31); // 64..95
    int* fself = &ctrs[1024 + xcd * 128];   // 96 per-wave self flags
    int* fx    = &ctrs[3072 + g * 128];     // 96 per-wave cross h1 flags

    const unsigned short* Wc = l ? W1cat : W0cat;
    const int Kc = l ? K1_ : K0_;
    int q0 = frow >> 3, col0 = c0 + (frow & 7);
    const unsigned short* Bp0 = Wc + (size_t)(q0 * H_ + col0) * Kc + kof;       // gates i,f
    const unsigned short* Bp1 = Wc + (size_t)((2 + q0) * H_ + col0) * Kc + kof; // gates g,o

    const float* bias = l ? bias1 : bias0;
    const bool lowhalf = (lane & 15) < 8;
    const int ecol = c0 + (lane & 7);
    float bi = 0.f, bff = 0.f, bg = 0.f, bo = 0.f;
    if (lowhalf) {
        bi  = bias[0 * H_ + ecol];
        bff = bias[1 * H_ + ecol];
        bg  = bias[2 * H_ + ecol];
        bo  = bias[3 * H_ + ecol];
    }
    float creg[4] = {0.f, 0.f, 0.f, 0.f};

    const size_t aoff = (size_t)q * 128 + (size_t)frow * 8;
    const size_t stoff_e = (size_t)cbw * 128 + (size_t)(lane >> 2) * 8
                         + (size_t)(lane & 3) * 2;

    if (l == 0) {
        // ------------- layer 0 domain: superstep s computes h1[s] -----------
        bf16x8 Bw0[26], Bw1[26];
        #pragma unroll
        for (int k = 0; k < 26; k++) {
            Bw0[k] = *(const bf16x8*)(Bp0 + k * 32);
            Bw1[k] = *(const bf16x8*)(Bp1 + k * 32);
        }
        #pragma unroll
        for (int k = 0; k < 26; k++) { PIN8A(Bw0[k]); PIN8A(Bw1[k]); }
        for (int s = 0; s < T_; ++s) {
            f32x4 acc0 = {0.f, 0.f, 0.f, 0.f};
            f32x4 acc1 = {0.f, 0.f, 0.f, 0.f};
            {
                const unsigned short* xsp =
                    xsT + ((size_t)s * B_ + m0 + frow) * IN_ + kof;
                bf16x8 ax0 = *(const bf16x8*)(xsp);
                bf16x8 ax1 = *(const bf16x8*)(xsp + 32);
                acc0 = MFMA16(ax0, Bw0[0], acc0);
                acc1 = MFMA16(ax0, Bw1[0], acc1);
                acc0 = MFMA16(ax1, Bw0[1], acc0);
                acc1 = MFMA16(ax1, Bw1[1], acc1);
            }
            if (s > 0) {
                POLL96(fself, s);   // every wave polls for itself; no barrier
                WAITV0();           // h1x[s-1] ack landed during poll (free)
                if (lane == 0)      // per-wave deferred cross publish
                    st_llc_u32((unsigned*)&fx[cbw], (unsigned)s);
                const unsigned short* hr =
                    h1loc + ((size_t)(s - 1) * 4 + g) * GSLOT_ + aoff;
                bf16x8 a[24];
                #pragma unroll
                for (int kj = 0; kj < 24; kj++)
                    a[kj] = *(const bf16x8*)(hr + kj * 512);
                #pragma unroll
                for (int kj = 0; kj < 24; kj++) {
                    acc0 = MFMA16(a[kj], Bw0[kj + 2], acc0);
                    acc1 = MFMA16(a[kj], Bw1[kj + 2], acc1);
                }
            }
            f32x4 pacc0, pacc1;
            #pragma unroll
            for (int j = 0; j < 4; j++) {
                pacc0[j] = __shfl_xor(acc0[j], 8);
                pacc1[j] = __shfl_xor(acc1[j], 8);
            }
            if (lowhalf) {
                #pragma unroll
                for (int j = 0; j < 4; j++) {
                    float pi = acc0[j]  + bi;
                    float pf = pacc0[j] + bff;
                    float pg = acc1[j]  + bg;
                    float po = pacc1[j] + bo;
                    float cn = fast_sigm(pf) * creg[j] + fast_sigm(pi) * fast_tanh(pg);
                    float hn = fast_sigm(po) * fast_tanh(cn);
                    creg[j] = cn;
                    ldsb[wave][q * 4 + j][lane & 7] = f2bf(hn);
                }
            }
            unsigned v = ((const unsigned*)&ldsb[wave][0][0])[lane];
            {
                size_t so = ((size_t)s * 4 + g) * GSLOT_ + stoff_e;
                *(unsigned*)(h1loc + so) = v;            // plain first (local)
                st_llc_u32((unsigned*)(h1x + so), v);    // sc1 second (cross)
            }
            WAITV1();   // retire h1loc ONLY; h1x keeps flying to the MALL
            if (lane == 0)   // own flag, own drain: no sibling wait
                st_llc_u32((unsigned*)&fself[cbw], (unsigned)(s + 1));
        }
        // final cross publish: h1x[T-1] ready (L1's s=T needs fx >= T)
        WAITV0();
        if (lane == 0) st_llc_u32((unsigned*)&fx[cbw], (unsigned)T_);
    } else {
        // ------------- layer 1 domain: superstep s computes h2[s-1] ---------
        // Weights: h1-half 48 frags + h2-half ki0..5 (12) pinned in AGPRs
        // (240 a-regs); h2-half ki6..23 (36 frags) staged in LDS.
        bf16x8 Bw0[24], Bw1[24];   // h1-half
        #pragma unroll
        for (int k = 0; k < 24; k++) {
            Bw0[k] = *(const bf16x8*)(Bp0 + k * 32);
            Bw1[k] = *(const bf16x8*)(Bp1 + k * 32);
        }
        bf16x8 Cw0[6], Cw1[6];     // h2-half ki 0..5
        #pragma unroll
        for (int k = 0; k < 6; k++) {
            Cw0[k] = *(const bf16x8*)(Bp0 + (24 + k) * 32);
            Cw1[k] = *(const bf16x8*)(Bp1 + (24 + k) * 32);
        }
        #pragma unroll
        for (int k = 0; k < 24; k++) { PIN8A(Bw0[k]); PIN8A(Bw1[k]); }
        #pragma unroll
        for (int k = 0; k < 6; k++)  { PIN8A(Cw0[k]); PIN8A(Cw1[k]); }
        #pragma unroll
        for (int f = 0; f < 18; f++) {   // stage ki = 6+f (per-wave slice)
            bf16x8 b0 = *(const bf16x8*)(Bp0 + (30 + f) * 32);
            bf16x8 b1 = *(const bf16x8*)(Bp1 + (30 + f) * 32);
            *(bf16x8*)&wstage[wave][2 * f][lane * 16]     = b0;
            *(bf16x8*)&wstage[wave][2 * f + 1][lane * 16] = b1;
        }
        for (int s = 1; s <= T_; ++s) {
            const int t = s - 1;
            {   // combined poll: fx >= s AND fself >= t (flags init 0 so
                // t=0 condition is trivially true)
                const int* p1 = &fx[i1];
                const int* p2 = &fx[i2];
                const int* p3 = &fself[i1];
                const int* p4 = &fself[i2];
                for (;;) {
                    int a = AGENT_LD(p1);
                    int b = AGENT_LD(p2);
                    int c = AGENT_LD(p3);
                    int d = AGENT_LD(p4);
                    if (__all(a >= s && b >= s && c >= t && d >= t)) break;
                    __builtin_amdgcn_s_sleep(1);
                }
                asm volatile("" ::: "memory");
            }
            f32x4 acc0 = {0.f, 0.f, 0.f, 0.f};
            f32x4 acc1 = {0.f, 0.f, 0.f, 0.f};
            const unsigned short* h1r = h1x + ((size_t)t * 4 + g) * GSLOT_ + aoff;
            if (t > 0) {
                const unsigned short* h2r =
                    h2loc + ((size_t)(t - 1) * 4 + g) * GSLOT_ + aoff;
                // FIFO order: a2 (local, fast) first, then a1 (cross, slow)
                bf16x8 a2[24];
                #pragma unroll
                for (int ki = 0; ki < 24; ki++)
                    a2[ki] = *(const bf16x8*)(h2r + ki * 512);
                bf16x8 a1[24];
                #pragma unroll
                for (int ki = 0; ki < 24; ki++)
                    a1[ki] = *(const bf16x8*)(h1r + ki * 512);
                // h2-half: ki0..5 AGPR B, ki6..23 LDS B -- runs while a1 flies
                #pragma unroll
                for (int ki = 0; ki < 6; ki++) {
                    acc0 = MFMA16(a2[ki], Cw0[ki], acc0);
                    acc1 = MFMA16(a2[ki], Cw1[ki], acc1);
                }
                #pragma unroll
                for (int ki = 6; ki < 24; ki++) {
                    int f = ki - 6;
                    bf16x8 b0 = *(const bf16x8*)&wstage[wave][2 * f][lane * 16];
                    bf16x8 b1 = *(const bf16x8*)&wstage[wave][2 * f + 1][lane * 16];
                    acc0 = MFMA16(a2[ki], b0, acc0);
                    acc1 = MFMA16(a2[ki], b1, acc1);
                }
                // h1-half: AGPR B, a1 landed by now
                #pragma unroll
                for (int ki = 0; ki < 24; ki++) {
                    acc0 = MFMA16(a1[ki], Bw0[ki], acc0);
                    acc1 = MFMA16(a1[ki], Bw1[ki], acc1);
                }
            } else {
                bf16x8 a1[24];
                #pragma unroll
                for (int ki = 0; ki < 24; ki++)
                    a1[ki] = *(const bf16x8*)(h1r + ki * 512);
                #pragma unroll
                for (int ki = 0; ki < 24; ki++) {
                    acc0 = MFMA16(a1[ki], Bw0[ki], acc0);
                    acc1 = MFMA16(a1[ki], Bw1[ki], acc1);
                }
            }
            f32x4 pacc0, pacc1;
            #pragma unroll
            for (int j = 0; j < 4; j++) {
                pacc0[j] = __shfl_xor(acc0[j], 8);
                pacc1[j] = __shfl_xor(acc1[j], 8);
            }
            if (lowhalf) {
                #pragma unroll
                for (int j = 0; j < 4; j++) {
                    int row = m0 + q * 4 + j;
                    float pi = acc0[j]  + bi;
                    float pf = pacc0[j] + bff;
                    float pg = acc1[j]  + bg;
                    float po = pacc1[j] + bo;
                    float cn = fast_sigm(pf) * creg[j] + fast_sigm(pi) * fast_tanh(pg);
                    float hn = fast_sigm(po) * fast_tanh(cn);
                    creg[j] = cn;
                    ldsb[wave][q * 4 + j][lane & 7] = f2bf(hn);
                    if (t == T_ - 1) hf32[(size_t)row * H_ + ecol] = hn;
                }
            }
            unsigned v = ((const unsigned*)&ldsb[wave][0][0])[lane];
            *(unsigned*)(h2loc + ((size_t)t * 4 + g) * GSLOT_ + stoff_e) = v;
            WAITV0();   // plain store, local ack (also drains hf32 at t=T-1)
            if (lane == 0)
                st_llc_u32((unsigned*)&fself[cbw], (unsigned)s);
        }
        if (xcd == 7 && cbw == 0 && lane == 0) st_llc_u32((unsigned*)done, 1u);
    }
}

// ---------------- head ----------------
__global__ __launch_bounds__(256) void head_kernel(
    const float* __restrict__ hlast,
    const float* __restrict__ W1, const float* __restrict__ b1,
    const float* __restrict__ W2, const float* __restrict__ b2,
    float* __restrict__ out)
{
    __shared__ float hs[H_];
    __shared__ float partial[4];
    int b = blockIdx.x;
    int tid = threadIdx.x;
    for (int j = tid; j < H_; j += 256) hs[j] = hlast[(size_t)b * H_ + j];
    __syncthreads();
    float z = 0.f;
    const float* w = W1 + (size_t)tid * H_;
    for (int j = 0; j < H_; j++) z += hs[j] * w[j];
    z += b1[tid];
    z = z / (1.0f + fabsf(z));
    float p = z * W2[tid];
    #pragma unroll
    for (int off = 32; off > 0; off >>= 1) p += __shfl_down(p, off, 64);
    if ((tid & 63) == 0) partial[tid >> 6] = p;
    __syncthreads();
    if (tid == 0) {
        float s = partial[0] + partial[1] + partial[2] + partial[3];
        out[b] = (s + b2[0]) * 70.0f;
    }
}

extern "C" void kernel_launch(void* const* d_in, const int* in_sizes, int n_in,
                              void* d_out, int out_size, void* d_ws, size_t ws_size,
                              hipStream_t stream) {
    const float* x    = (const float*)d_in[0];
    const float* Wih0 = (const float*)d_in[1];
    const float* Whh0 = (const float*)d_in[2];
    const float* bih0 = (const float*)d_in[3];
    const float* bhh0 = (const float*)d_in[4];
    const float* Wih1 = (const float*)d_in[5];
    const float* Whh1 = (const float*)d_in[6];
    const float* bih1 = (const float*)d_in[7];
    const float* bhh1 = (const float*)d_in[8];
    const float* W1   = (const float*)d_in[9];
    const float* b1   = (const float*)d_in[10];
    const float* W2   = (const float*)d_in[11];
    const float* b2   = (const float*)d_in[12];
    float* out = (float*)d_out;

    const size_t RING = (size_t)T_ * 4 * GSLOT_ * 2;   // 24 MB each

    char* w = (char*)d_ws;
    int* ctrs = (int*)w;                          w += 65536;
    unsigned short* h1loc = (unsigned short*)w;   w += RING;
    unsigned short* h1x   = (unsigned short*)w;   w += RING;
    unsigned short* h2loc = (unsigned short*)w;   w += RING;
    unsigned short* xsT   = (unsigned short*)w;   w += (size_t)B_ * T_ * IN_ * 2;
    unsigned short* W0cat = (unsigned short*)w;   w += (size_t)G_ * K0_ * 2;
    unsigned short* W1cat = (unsigned short*)w;   w += (size_t)G_ * K1_ * 2;
    float* bias0 = (float*)w;                     w += G_ * 4;
    float* bias1 = (float*)w;                     w += G_ * 4;
    float* hf32  = (float*)w;                     w += (size_t)B_ * H_ * 4;

    prep_kernel<<<1024, 256, 0, stream>>>(x, Wih0, Whh0, bih0, bhh0,
                                          Wih1, Whh1, bih1, bhh1,
                                          xsT, W0cat, W1cat, bias0, bias1, ctrs);
    lstm_persistent<<<NWGT, 256, 0, stream>>>(xsT, W0cat, W1cat, bias0, bias1,
                                              h1loc, h1x, h2loc, hf32, ctrs);
    head_kernel<<<B_, 256, 0, stream>>>(hf32, W1, b1, W2, b2, out);
}

// Round 14
// 1732.052 us; speedup vs baseline: 2.1201x; 1.6882x over previous
//
#include <hip/hip_runtime.h>
#include <hip/hip_bf16.h>

// LSTM_Net round 24: r20 base (r23 reverted) + per-epoch WRITE-ONCE flag
// lines.
// r22/r23 lesson: sync cost scales with publisher/poller count per round;
// r20's shape (24 packed flags, one polling wave, 2 barriers) is optimal on
// that axis. Last untested flag variable: TEMPORAL reuse. Every flag line
// is rewritten 256x while continuously polled -- each step's 24 sc1 stores
// interleave with ~24 pollers' reads on the SAME MALL line, and step s+1's
// stores land while step s's consumers still poll it. Fix: flags become
// F[dom][epoch][24] -- one fresh 128B line per (domain, step), write-once
// slots, polled only in their own step window. Same counts/geometry/roles
// as r20; only address freshness changes. ctrs grows to 1MB (prep zeroes).
// Semantics: F0[e]: h1[e-1] stored locally (L0 end of step s sets F0[s+1];
// L0 step s polls F0[s]). FX[e]: h1x[e-1] drained (L0 top of step s sets
// FX[s], post-loop FX[T]; L1 step s polls FX[s]). F1[e]: h2[e-1] stored
// (L1 end of step s sets F1[s]; L1 step s polls F1[s-1] when t>0).
// Layout (ints): roles [0..7], done [63], F0/F1 at FS_+(dom*260+e)*32+i,
// FX at FX_+(g*260+e)*32+i.

#define B_  64
#define T_  256
#define IN_ 64
#define H_  768
#define G_  3072   // 4*H
#define K0_ 832    // IN_ + H_
#define K1_ 1536   // 2*H_
#define NWGT 256
#define GSLOT_ 12288   // per (t,group) ring slot elems = 96cbw * 16rows * 8cols
#define FS_ 4096
#define FX_ 70656

typedef __bf16 bf16_t;
typedef bf16_t bf16x8 __attribute__((ext_vector_type(8)));
typedef float  f32x4  __attribute__((ext_vector_type(4)));

__device__ __forceinline__ unsigned short f2bf(float f) {
    union { float f; unsigned u; } v; v.f = f;
    unsigned r = v.u + 0x7FFFu + ((v.u >> 16) & 1u);
    return (unsigned short)(r >> 16);
}
__device__ __forceinline__ float fast_sigm(float x) {
    float e = __builtin_amdgcn_exp2f(-1.44269504f * x);
    return __builtin_amdgcn_rcpf(1.0f + e);
}
__device__ __forceinline__ float fast_tanh(float x) {
    float e = __builtin_amdgcn_exp2f(2.88539008f * x);
    return (e - 1.0f) * __builtin_amdgcn_rcpf(e + 1.0f);
}
__device__ __forceinline__ void st_llc_u32(unsigned* p, unsigned v) {
    asm volatile("global_store_dword %0, %1, off sc1" :: "v"(p), "v"(v) : "memory");
}
#define MFMA16(a, b, c) __builtin_amdgcn_mfma_f32_16x16x32_bf16((a), (b), (c), 0, 0, 0)
#define AGENT_LD(p) __hip_atomic_load((p), __ATOMIC_RELAXED, __HIP_MEMORY_SCOPE_AGENT)
#define PIN8A(v) asm volatile("" : "+a"(v))
#define BAR() do { __builtin_amdgcn_s_barrier(); \
                   asm volatile("" ::: "memory"); } while (0)
#define WAITV0() asm volatile("s_waitcnt vmcnt(0)" ::: "memory")
#define WAITV1() asm volatile("s_waitcnt vmcnt(1)" ::: "memory")

// ---------------- prep ----------------
__global__ __launch_bounds__(256) void prep_kernel(
    const float* __restrict__ x,
    const float* __restrict__ Wih0, const float* __restrict__ Whh0,
    const float* __restrict__ bih0, const float* __restrict__ bhh0,
    const float* __restrict__ Wih1, const float* __restrict__ Whh1,
    const float* __restrict__ bih1, const float* __restrict__ bhh1,
    unsigned short* __restrict__ xsT,    // [T][B][64]
    unsigned short* __restrict__ W0cat,  // [3072][832]
    unsigned short* __restrict__ W1cat,  // [3072][1536]
    float* __restrict__ bias0, float* __restrict__ bias1,
    int* __restrict__ ctrs)              // [262144] (1 MB)
{
    int i = blockIdx.x * blockDim.x + threadIdx.x;
    int stride = gridDim.x * blockDim.x;
    for (int j = i; j < B_ * T_ * IN_; j += stride) {
        int b = j >> 14;
        int t = (j >> 6) & (T_ - 1);
        int k = j & (IN_ - 1);
        xsT[(((size_t)t * B_) + b) * IN_ + k] = f2bf(x[j] * (1.0f / 1.5f));
    }
    for (int j = i; j < G_ * IN_; j += stride) {
        int r = j >> 6; int k = j & 63;
        W0cat[(size_t)r * K0_ + k] = f2bf(Wih0[j]);
    }
    for (int j = i; j < G_ * H_; j += stride) {
        int r = j / H_; int k = j - r * H_;
        W0cat[(size_t)r * K0_ + IN_ + k] = f2bf(Whh0[j]);
        W1cat[(size_t)r * K1_ + k]       = f2bf(Wih1[j]);
        W1cat[(size_t)r * K1_ + H_ + k]  = f2bf(Whh1[j]);
    }
    for (int j = i; j < G_; j += stride) {
        bias0[j] = bih0[j] + bhh0[j];
        bias1[j] = bih1[j] + bhh1[j];
    }
    for (int j = i; j < 262144; j += stride) ctrs[j] = 0;
}

// ---------------- persistent XCD-domain recurrence ----------------
__global__ __launch_bounds__(256, 1) void lstm_persistent(
    const unsigned short* __restrict__ xsT,
    const unsigned short* __restrict__ W0cat,
    const unsigned short* __restrict__ W1cat,
    const float* __restrict__ bias0, const float* __restrict__ bias1,
    unsigned short* __restrict__ h1loc,  // [T][4g][96cbw][16][8] plain/local
    unsigned short* __restrict__ h1x,    // [T][4g][96cbw][16][8] sc1/cross
    unsigned short* __restrict__ h2loc,  // [T][4g][96cbw][16][8] plain/local
    float* __restrict__ hf32,            // [B][H] fp32 (t = T-1)
    int* __restrict__ ctrs)
{
    __shared__ unsigned short ldsb[4][16][8];
    // 144KB weight stage (L1 waves: 36 frags x 1KB each). Forces 1 WG/CU.
    __shared__ char wstage[4][36][1024];
    __shared__ int role_s;

    const int tid  = threadIdx.x;
    const int lane = tid & 63;
    const int wave = tid >> 6;

    int xcd;
    asm volatile("s_getreg_b32 %0, hwreg(HW_REG_XCC_ID)" : "=s"(xcd));
    xcd &= 7;

    if (tid == 0) role_s = atomicAdd(&ctrs[xcd], 1);
    __syncthreads();
    const int role = role_s;

    int* done = &ctrs[63];

    // ---------- heater roles: pin GFX clock; poll dedicated done line ------
    if (role >= 24) {
        float a = 1.0f + (float)tid * 1e-7f;
        const float bm = 1.0000001f, cm = 1e-9f;
        for (;;) {
            for (int i = 0; i < 2048; i++)
                a = __builtin_fmaf(a, bm, cm);
            asm volatile("" : "+v"(a));
            int d = 0;
            if (lane == 0) d = AGENT_LD(done);
            d = __builtin_amdgcn_readfirstlane(d);
            if (d != 0) break;
        }
        return;
    }

    const int l  = xcd & 1;          // layer handled by this XCD
    const int g  = xcd >> 1;         // batch group (16 rows)
    const int m0 = g * 16;           // group's batch-row base
    const int cbw = role * 4 + wave; // H-col block 0..95 (8 cols each)
    const int c0  = cbw * 8;
    const int frow = lane & 15;
    const int q    = lane >> 4;
    const int kof  = q * 8;

    int fidx = lane; if (fidx >= 48) fidx -= 48; if (fidx >= 24) fidx -= 24;
    // per-epoch write-once flag lines
    int* fsD = &ctrs[FS_ + xcd * 260 * 32];   // this domain's F (F0 or F1)
    int* fxG = &ctrs[FX_ + g * 260 * 32];     // group g's FX

    const unsigned short* Wc = l ? W1cat : W0cat;
    const int Kc = l ? K1_ : K0_;
    int q0 = frow >> 3, col0 = c0 + (frow & 7);
    const unsigned short* Bp0 = Wc + (size_t)(q0 * H_ + col0) * Kc + kof;       // gates i,f
    const unsigned short* Bp1 = Wc + (size_t)((2 + q0) * H_ + col0) * Kc + kof; // gates g,o

    const float* bias = l ? bias1 : bias0;
    const bool lowhalf = (lane & 15) < 8;
    const int ecol = c0 + (lane & 7);
    float bi = 0.f, bff = 0.f, bg = 0.f, bo = 0.f;
    if (lowhalf) {
        bi  = bias[0 * H_ + ecol];
        bff = bias[1 * H_ + ecol];
        bg  = bias[2 * H_ + ecol];
        bo  = bias[3 * H_ + ecol];
    }
    float creg[4] = {0.f, 0.f, 0.f, 0.f};

    const size_t aoff = (size_t)q * 128 + (size_t)frow * 8;
    const size_t stoff_e = (size_t)cbw * 128 + (size_t)(lane >> 2) * 8
                         + (size_t)(lane & 3) * 2;

    if (l == 0) {
        // ------------- layer 0 domain: superstep s computes h1[s] -----------
        bf16x8 Bw0[26], Bw1[26];
        #pragma unroll
        for (int k = 0; k < 26; k++) {
            Bw0[k] = *(const bf16x8*)(Bp0 + k * 32);
            Bw1[k] = *(const bf16x8*)(Bp1 + k * 32);
        }
        #pragma unroll
        for (int k = 0; k < 26; k++) { PIN8A(Bw0[k]); PIN8A(Bw1[k]); }
        for (int s = 0; s < T_; ++s) {
            f32x4 acc0 = {0.f, 0.f, 0.f, 0.f};
            f32x4 acc1 = {0.f, 0.f, 0.f, 0.f};
            {
                const unsigned short* xsp =
                    xsT + ((size_t)s * B_ + m0 + frow) * IN_ + kof;
                bf16x8 ax0 = *(const bf16x8*)(xsp);
                bf16x8 ax1 = *(const bf16x8*)(xsp + 32);
                acc0 = MFMA16(ax0, Bw0[0], acc0);
                acc1 = MFMA16(ax0, Bw1[0], acc1);
                acc0 = MFMA16(ax1, Bw0[1], acc0);
                acc1 = MFMA16(ax1, Bw1[1], acc1);
            }
            if (s > 0) {
                if (wave == 0) {   // F0[s]: h1[s-1] stored (write-once line)
                    const int* fp = &fsD[s * 32 + fidx];
                    for (;;) {
                        int v = AGENT_LD(fp);
                        if (__all(v != 0)) break;
                        __builtin_amdgcn_s_sleep(1);
                    }
                }
                WAITV0();   // prev h1x ack: landed during poll window (free)
                BAR();      // B1: h1loc[s-1] ready AND h1x[s-1] drained
                if (tid == 0)   // deferred cross publish: FX[s] = h1x[s-1] ok
                    st_llc_u32((unsigned*)&fxG[s * 32 + role], 1u);
                const unsigned short* hr =
                    h1loc + ((size_t)(s - 1) * 4 + g) * GSLOT_ + aoff;
                bf16x8 a[24];
                #pragma unroll
                for (int kj = 0; kj < 24; kj++)
                    a[kj] = *(const bf16x8*)(hr + kj * 512);
                #pragma unroll
                for (int kj = 0; kj < 24; kj++) {
                    acc0 = MFMA16(a[kj], Bw0[kj + 2], acc0);
                    acc1 = MFMA16(a[kj], Bw1[kj + 2], acc1);
                }
            }
            f32x4 pacc0, pacc1;
            #pragma unroll
            for (int j = 0; j < 4; j++) {
                pacc0[j] = __shfl_xor(acc0[j], 8);
                pacc1[j] = __shfl_xor(acc1[j], 8);
            }
            if (lowhalf) {
                #pragma unroll
                for (int j = 0; j < 4; j++) {
                    float pi = acc0[j]  + bi;
                    float pf = pacc0[j] + bff;
                    float pg = acc1[j]  + bg;
                    float po = pacc1[j] + bo;
                    float cn = fast_sigm(pf) * creg[j] + fast_sigm(pi) * fast_tanh(pg);
                    float hn = fast_sigm(po) * fast_tanh(cn);
                    creg[j] = cn;
                    ldsb[wave][q * 4 + j][lane & 7] = f2bf(hn);
                }
            }
            unsigned v = ((const unsigned*)&ldsb[wave][0][0])[lane];
            {
                size_t so = ((size_t)s * 4 + g) * GSLOT_ + stoff_e;
                *(unsigned*)(h1loc + so) = v;            // plain first (local)
                st_llc_u32((unsigned*)(h1x + so), v);    // sc1 second (cross)
            }
            WAITV1();   // retire h1loc ONLY; h1x keeps flying to the MALL
            BAR();      // B2: all waves' h1loc visible in local L2
            if (tid == 0)   // F0[s+1]: h1[s] stored (fresh line)
                st_llc_u32((unsigned*)&fsD[(s + 1) * 32 + role], 1u);
        }
        // final cross publish: FX[T] = h1x[T-1] drained
        WAITV0();
        BAR();
        if (tid == 0) st_llc_u32((unsigned*)&fxG[T_ * 32 + role], 1u);
    } else {
        // ------------- layer 1 domain: superstep s computes h2[s-1] ---------
        // Weights: h1-half 48 frags + h2-half ki0..5 (12) pinned in AGPRs
        // (240 a-regs); h2-half ki6..23 (36 frags) staged in LDS.
        bf16x8 Bw0[24], Bw1[24];   // h1-half
        #pragma unroll
        for (int k = 0; k < 24; k++) {
            Bw0[k] = *(const bf16x8*)(Bp0 + k * 32);
            Bw1[k] = *(const bf16x8*)(Bp1 + k * 32);
        }
        bf16x8 Cw0[6], Cw1[6];     // h2-half ki 0..5
        #pragma unroll
        for (int k = 0; k < 6; k++) {
            Cw0[k] = *(const bf16x8*)(Bp0 + (24 + k) * 32);
            Cw1[k] = *(const bf16x8*)(Bp1 + (24 + k) * 32);
        }
        #pragma unroll
        for (int k = 0; k < 24; k++) { PIN8A(Bw0[k]); PIN8A(Bw1[k]); }
        #pragma unroll
        for (int k = 0; k < 6; k++)  { PIN8A(Cw0[k]); PIN8A(Cw1[k]); }
        #pragma unroll
        for (int f = 0; f < 18; f++) {   // stage ki = 6+f (per-wave slice)
            bf16x8 b0 = *(const bf16x8*)(Bp0 + (30 + f) * 32);
            bf16x8 b1 = *(const bf16x8*)(Bp1 + (30 + f) * 32);
            *(bf16x8*)&wstage[wave][2 * f][lane * 16]     = b0;
            *(bf16x8*)&wstage[wave][2 * f + 1][lane * 16] = b1;
        }
        for (int s = 1; s <= T_; ++s) {
            const int t = s - 1;
            if (wave == 0) {   // FX[s]: h1x[t] ready cross-die
                const int* fp = &fxG[s * 32 + fidx];
                for (;;) {
                    int v = AGENT_LD(fp);
                    if (__all(v != 0)) break;
                    __builtin_amdgcn_s_sleep(1);
                }
            }
            if (wave == 1 && t > 0) {   // F1[t]: h2[t-1] stored locally
                const int* fp = &fsD[t * 32 + fidx];
                for (;;) {
                    int v = AGENT_LD(fp);
                    if (__all(v != 0)) break;
                    __builtin_amdgcn_s_sleep(1);
                }
            }
            WAITV0();   // prev h2loc plain store: local ack, cheap
            BAR();
            f32x4 acc0 = {0.f, 0.f, 0.f, 0.f};
            f32x4 acc1 = {0.f, 0.f, 0.f, 0.f};
            const unsigned short* h1r = h1x + ((size_t)t * 4 + g) * GSLOT_ + aoff;
            if (t > 0) {
                const unsigned short* h2r =
                    h2loc + ((size_t)(t - 1) * 4 + g) * GSLOT_ + aoff;
                // FIFO order: a2 (local, fast) first, then a1 (cross, slow)
                bf16x8 a2[24];
                #pragma unroll
                for (int ki = 0; ki < 24; ki++)
                    a2[ki] = *(const bf16x8*)(h2r + ki * 512);
                bf16x8 a1[24];
                #pragma unroll
                for (int ki = 0; ki < 24; ki++)
                    a1[ki] = *(const bf16x8*)(h1r + ki * 512);
                // h2-half: ki0..5 AGPR B, ki6..23 LDS B -- runs while a1 flies
                #pragma unroll
                for (int ki = 0; ki < 6; ki++) {
                    acc0 = MFMA16(a2[ki], Cw0[ki], acc0);
                    acc1 = MFMA16(a2[ki], Cw1[ki], acc1);
                }
                #pragma unroll
                for (int ki = 6; ki < 24; ki++) {
                    int f = ki - 6;
                    bf16x8 b0 = *(const bf16x8*)&wstage[wave][2 * f][lane * 16];
                    bf16x8 b1 = *(const bf16x8*)&wstage[wave][2 * f + 1][lane * 16];
                    acc0 = MFMA16(a2[ki], b0, acc0);
                    acc1 = MFMA16(a2[ki], b1, acc1);
                }
                // h1-half: AGPR B, a1 landed by now
                #pragma unroll
                for (int ki = 0; ki < 24; ki++) {
                    acc0 = MFMA16(a1[ki], Bw0[ki], acc0);
                    acc1 = MFMA16(a1[ki], Bw1[ki], acc1);
                }
            } else {
                bf16x8 a1[24];
                #pragma unroll
                for (int ki = 0; ki < 24; ki++)
                    a1[ki] = *(const bf16x8*)(h1r + ki * 512);
                #pragma unroll
                for (int ki = 0; ki < 24; ki++) {
                    acc0 = MFMA16(a1[ki], Bw0[ki], acc0);
                    acc1 = MFMA16(a1[ki], Bw1[ki], acc1);
                }
            }
            f32x4 pacc0, pacc1;
            #pragma unroll
            for (int j = 0; j < 4; j++) {
                pacc0[j] = __shfl_xor(acc0[j], 8);
                pacc1[j] = __shfl_xor(acc1[j], 8);
            }
            if (lowhalf) {
                #pragma unroll
                for (int j = 0; j < 4; j++) {
                    int row = m0 + q * 4 + j;
                    float pi = acc0[j]  + bi;
                    float pf = pacc0[j] + bff;
                    float pg = acc1[j]  + bg;
                    float po = pacc1[j] + bo;
                    float cn = fast_sigm(pf) * creg[j] + fast_sigm(pi) * fast_tanh(pg);
                    float hn = fast_sigm(po) * fast_tanh(cn);
                    creg[j] = cn;
                    ldsb[wave][q * 4 + j][lane & 7] = f2bf(hn);
                    if (t == T_ - 1) hf32[(size_t)row * H_ + ecol] = hn;
                }
            }
            unsigned v = ((const unsigned*)&ldsb[wave][0][0])[lane];
            *(unsigned*)(h2loc + ((size_t)t * 4 + g) * GSLOT_ + stoff_e) = v;
            WAITV0();   // plain store, local ack
            BAR();
            if (tid == 0)   // F1[s]: h2[s-1] stored (fresh line)
                st_llc_u32((unsigned*)&fsD[s * 32 + role], 1u);
        }
        if (xcd == 7 && role == 0 && tid == 0) st_llc_u32((unsigned*)done, 1u);
    }
}

// ---------------- head ----------------
__global__ __launch_bounds__(256) void head_kernel(
    const float* __restrict__ hlast,
    const float* __restrict__ W1, const float* __restrict__ b1,
    const float* __restrict__ W2, const float* __restrict__ b2,
    float* __restrict__ out)
{
    __shared__ float hs[H_];
    __shared__ float partial[4];
    int b = blockIdx.x;
    int tid = threadIdx.x;
    for (int j = tid; j < H_; j += 256) hs[j] = hlast[(size_t)b * H_ + j];
    __syncthreads();
    float z = 0.f;
    const float* w = W1 + (size_t)tid * H_;
    for (int j = 0; j < H_; j++) z += hs[j] * w[j];
    z += b1[tid];
    z = z / (1.0f + fabsf(z));
    float p = z * W2[tid];
    #pragma unroll
    for (int off = 32; off > 0; off >>= 1) p += __shfl_down(p, off, 64);
    if ((tid & 63) == 0) partial[tid >> 6] = p;
    __syncthreads();
    if (tid == 0) {
        float s = partial[0] + partial[1] + partial[2] + partial[3];
        out[b] = (s + b2[0]) * 70.0f;
    }
}

extern "C" void kernel_launch(void* const* d_in, const int* in_sizes, int n_in,
                              void* d_out, int out_size, void* d_ws, size_t ws_size,
                              hipStream_t stream) {
    const float* x    = (const float*)d_in[0];
    const float* Wih0 = (const float*)d_in[1];
    const float* Whh0 = (const float*)d_in[2];
    const float* bih0 = (const float*)d_in[3];
    const float* bhh0 = (const float*)d_in[4];
    const float* Wih1 = (const float*)d_in[5];
    const float* Whh1 = (const float*)d_in[6];
    const float* bih1 = (const float*)d_in[7];
    const float* bhh1 = (const float*)d_in[8];
    const float* W1   = (const float*)d_in[9];
    const float* b1   = (const float*)d_in[10];
    const float* W2   = (const float*)d_in[11];
    const float* b2   = (const float*)d_in[12];
    float* out = (float*)d_out;

    const size_t RING = (size_t)T_ * 4 * GSLOT_ * 2;   // 24 MB each

    char* w = (char*)d_ws;
    int* ctrs = (int*)w;                          w += 1048576;   // 1 MB flags
    unsigned short* h1loc = (unsigned short*)w;   w += RING;
    unsigned short* h1x   = (unsigned short*)w;   w += RING;
    unsigned short* h2loc = (unsigned short*)w;   w += RING;
    unsigned short* xsT   = (unsigned short*)w;   w += (size_t)B_ * T_ * IN_ * 2;
    unsigned short* W0cat = (unsigned short*)w;   w += (size_t)G_ * K0_ * 2;
    unsigned short* W1cat = (unsigned short*)w;   w += (size_t)G_ * K1_ * 2;
    float* bias0 = (float*)w;                     w += G_ * 4;
    float* bias1 = (float*)w;                     w += G_ * 4;
    float* hf32  = (float*)w;                     w += (size_t)B_ * H_ * 4;

    prep_kernel<<<1024, 256, 0, stream>>>(x, Wih0, Whh0, bih0, bhh0,
                                          Wih1, Whh1, bih1, bhh1,
                                          xsT, W0cat, W1cat, bias0, bias1, ctrs);
    lstm_persistent<<<NWGT, 256, 0, stream>>>(xsT, W0cat, W1cat, bias0, bias1,
                                              h1loc, h1x, h2loc, hf32, ctrs);
    head_kernel<<<B_, 256, 0, stream>>>(hf32, W1, b1, W2, b2, out);
}